// Round 1
// 446.740 us; speedup vs baseline: 1.0902x; 1.0902x over previous
//
#include <hip/hip_runtime.h>

// Problem constants
#define DD   512
#define KK_N 32
#define HH   4
#define DH   128
#define BN_TOT 4096

typedef __bf16 bf16x8 __attribute__((ext_vector_type(8)));
typedef float  f32x4  __attribute__((ext_vector_type(4)));

__device__ __forceinline__ unsigned rne_bf16(float x) {
    unsigned u = __float_as_uint(x);
    return (u + 0x7fffu + ((u >> 16) & 1u)) >> 16;
}

// ---------------------------------------------------------------------------
// One-time prep: WkT[h][o][k] = Wk[h*128 + k][o]  (fp32, 1 MB total)
// grid (16, 4): block = (32-wide o-chunk, head). LDS-tiled transpose.
// ---------------------------------------------------------------------------
__global__ __launch_bounds__(256)
void prep_wkT(const float* __restrict__ Wk, float* __restrict__ WkT)
{
    __shared__ float tile[32][DH + 1];
    const int h = blockIdx.y, o0 = blockIdx.x * 32, t = threadIdx.x;
#pragma unroll
    for (int r = 0; r < 16; r++) {
        int k = (t >> 5) + r * 8;                       // 0..127
        tile[t & 31][k] = Wk[(long)(h * DH + k) * DD + o0 + (t & 31)];
    }
    __syncthreads();
#pragma unroll
    for (int r = 0; r < 16; r++) {
        int ol = (t >> 7) + r * 2;                      // 0..31
        WkT[((long)h * DD + o0 + ol) * DH + (t & 127)] = tile[ol][t & 127];
    }
}

// ---------------------------------------------------------------------------
// bf16x2-split MFMA GEMM (NT):  C[r][o] = sum_k A[r*lda+k] * B[o*ldb+k] (+bias[o])
// fp32 in / fp32 out; inputs converted to bf16 hi/lo during LDS staging; math
// on v_mfma_f32_16x16x32_bf16 as Ahi*Bhi + Ahi*Blo + Alo*Bhi (lo*lo ~2^-32, dropped).
// 256 threads = 4 waves in a 2x2 wave grid; per-wave tile (BM/2)x(BN/2).
// blockIdx.z offsets operands by sA/sB/sC/sBias (per-head slices).
// LDS row layout (per matrix row): k-group g=k/8 at elem offset g*16 + comp*8 + k%8
// (hi=comp0, lo=comp1), row stride 2*BK+8 = 136 bf16 = 272B -> even bank spread.
// ---------------------------------------------------------------------------
template<int BM, int BN>
__global__ __launch_bounds__(256)
void gemm_bf16x2(const float* __restrict__ A, int lda, long sA,
                 const float* __restrict__ B, int ldb, long sB,
                 float*       __restrict__ C, int ldc, long sC,
                 const float* __restrict__ bias, int sBias,
                 int Kd)
{
    constexpr int BK  = 64;
    constexpr int LDW = 2 * BK + 8;                 // 136 bf16 per row
    constexpr int A_LOADS = BM * BK / 1024;         // float4 rounds of 256 thr
    constexpr int B_LOADS = BN * BK / 1024;
    constexpr int WM = BM / 2, WN = BN / 2;
    constexpr int MI = WM / 16, NI = WN / 16;

    const int z = blockIdx.z;
    A += (long)z * sA;
    B += (long)z * sB;
    C += (long)z * sC;
    if (bias) bias += (long)z * sBias;

    __shared__ __align__(16) unsigned short As[BM * LDW];
    __shared__ __align__(16) unsigned short Bs[BN * LDW];

    const int t    = threadIdx.x;
    const int lane = t & 63;
    const int wave = t >> 6;
    const int wm   = wave >> 1, wn = wave & 1;
    const int rbase = blockIdx.y * BM;
    const int obase = blockIdx.x * BN;

    float4 areg[A_LOADS], breg[B_LOADS];
    auto loadAB = [&](int k0) {
#pragma unroll
        for (int i = 0; i < A_LOADS; i++) {
            int s = t + i * 256, k4 = s & 15, row = s >> 4;
            areg[i] = *(const float4*)&A[(long)(rbase + row) * lda + k0 + k4 * 4];
        }
#pragma unroll
        for (int i = 0; i < B_LOADS; i++) {
            int s = t + i * 256, k4 = s & 15, row = s >> 4;
            breg[i] = *(const float4*)&B[(long)(obase + row) * ldb + k0 + k4 * 4];
        }
    };
    auto cvt_store = [&](unsigned short* dst, float4 v, int row, int k4) {
        unsigned h0 = rne_bf16(v.x), h1 = rne_bf16(v.y);
        unsigned h2 = rne_bf16(v.z), h3 = rne_bf16(v.w);
        float l0 = v.x - __uint_as_float(h0 << 16);
        float l1 = v.y - __uint_as_float(h1 << 16);
        float l2 = v.z - __uint_as_float(h2 << 16);
        float l3 = v.w - __uint_as_float(h3 << 16);
        int off = row * LDW + (k4 >> 1) * 16 + (k4 & 1) * 4;
        uint2 hw = make_uint2(h0 | (h1 << 16), h2 | (h3 << 16));
        uint2 lw = make_uint2(rne_bf16(l0) | (rne_bf16(l1) << 16),
                              rne_bf16(l2) | (rne_bf16(l3) << 16));
        *(uint2*)&dst[off]     = hw;   // hi half of this 8-k group
        *(uint2*)&dst[off + 8] = lw;   // lo half
    };

    f32x4 acc[MI][NI];
#pragma unroll
    for (int m = 0; m < MI; m++)
#pragma unroll
        for (int n = 0; n < NI; n++)
            acc[m][n] = (f32x4){0.f, 0.f, 0.f, 0.f};

    // fragment base: row/col = (lane&15) within 16x16, k-block = (lane>>4)*8
    const int a_base = (wm * WM + (lane & 15)) * LDW + (lane >> 4) * 16;
    const int b_base = (wn * WN + (lane & 15)) * LDW + (lane >> 4) * 16;

    loadAB(0);
    for (int k0 = 0; k0 < Kd; k0 += BK) {
        __syncthreads();
#pragma unroll
        for (int i = 0; i < A_LOADS; i++) { int s = t + i * 256; cvt_store(As, areg[i], s >> 4, s & 15); }
#pragma unroll
        for (int i = 0; i < B_LOADS; i++) { int s = t + i * 256; cvt_store(Bs, breg[i], s >> 4, s & 15); }
        __syncthreads();
        if (k0 + BK < Kd) loadAB(k0 + BK);   // prefetch overlaps compute

#pragma unroll
        for (int ks = 0; ks < 2; ks++) {
            bf16x8 ah[MI], al[MI], bh[NI], bl[NI];
#pragma unroll
            for (int m = 0; m < MI; m++) {
                ah[m] = *(const bf16x8*)&As[a_base + m * 16 * LDW + ks * 64];
                al[m] = *(const bf16x8*)&As[a_base + m * 16 * LDW + ks * 64 + 8];
            }
#pragma unroll
            for (int n = 0; n < NI; n++) {
                bh[n] = *(const bf16x8*)&Bs[b_base + n * 16 * LDW + ks * 64];
                bl[n] = *(const bf16x8*)&Bs[b_base + n * 16 * LDW + ks * 64 + 8];
            }
            // 3 independent sweeps -> 8 independent MFMAs each (pipeline-friendly)
#pragma unroll
            for (int m = 0; m < MI; m++)
#pragma unroll
                for (int n = 0; n < NI; n++)
                    acc[m][n] = __builtin_amdgcn_mfma_f32_16x16x32_bf16(ah[m], bh[n], acc[m][n], 0, 0, 0);
#pragma unroll
            for (int m = 0; m < MI; m++)
#pragma unroll
                for (int n = 0; n < NI; n++)
                    acc[m][n] = __builtin_amdgcn_mfma_f32_16x16x32_bf16(ah[m], bl[n], acc[m][n], 0, 0, 0);
#pragma unroll
            for (int m = 0; m < MI; m++)
#pragma unroll
                for (int n = 0; n < NI; n++)
                    acc[m][n] = __builtin_amdgcn_mfma_f32_16x16x32_bf16(al[m], bh[n], acc[m][n], 0, 0, 0);
        }
    }

    // epilogue: C/D layout col = lane&15, row = (lane>>4)*4 + reg  [m89-verified]
#pragma unroll
    for (int n = 0; n < NI; n++) {
        int col = obase + wn * WN + n * 16 + (lane & 15);
        float bv_ = bias ? bias[col] : 0.f;
#pragma unroll
        for (int m = 0; m < MI; m++) {
            int row0 = rbase + wm * WM + m * 16 + (lane >> 4) * 4;
#pragma unroll
            for (int j = 0; j < 4; j++)
                C[(long)(row0 + j) * ldc + col] = acc[m][n][j] + bv_;
        }
    }
}

// ---------------------------------------------------------------------------
// Fused scores -> masked online softmax -> attention-weighted embedding sum.
// One block per (b,n). wne may alias g (read fully before written, same block).
// (unchanged from previous round)
// ---------------------------------------------------------------------------
__global__ __launch_bounds__(256)
void attn_fused(const float* __restrict__ ne,    // [BN][32][512]
                const int*   __restrict__ mask,  // [BN][32]
                const float* __restrict__ q,     // [BN][512]
                const float* g,                  // [BN][4][512]  (no restrict: aliases wne)
                const float* __restrict__ bk,    // [512]
                float* wne)                      // [BN][4][512]
{
    const int bn   = blockIdx.x;
    const int t    = threadIdx.x;
    const int wave = t >> 6;
    const int lane = t & 63;

    __shared__ __align__(16) float ne_s[16][516];   // chunk of 16 neighbors, padded
    __shared__ __align__(16) float g_s[HH * DD];
    __shared__ float part[4][16][HH];               // [wave][k][h]
    __shared__ float p_s[HH][16];
    __shared__ float c_s[HH];
    __shared__ float m_s[HH], l_s[HH], alpha_s[HH];

    // stage g (query-side projected vectors), 2048 floats
    {
        const float4* gs = (const float4*)(g + (long)bn * (HH * DD));
        float4 v0 = gs[t];
        float4 v1 = gs[t + 256];
        *(float4*)&g_s[t * 4]         = v0;
        *(float4*)&g_s[(t + 256) * 4] = v1;
    }
    // c[h] = q_h . bk_h   (wave w handles head w; 64 lanes x 2 elems = 128)
    {
        float2 q2 = *(const float2*)&q[(long)bn * DD + wave * DH + lane * 2];
        float2 b2 = *(const float2*)&bk[wave * DH + lane * 2];
        float cp = q2.x * b2.x + q2.y * b2.y;
#pragma unroll
        for (int off = 32; off >= 1; off >>= 1)
            cp += __shfl_xor(cp, off, 64);
        if (lane == 0) c_s[wave] = cp;
    }
    if (t < HH) { m_s[t] = -__builtin_inff(); l_s[t] = 0.f; }

    float wacc[8] = {};
    const int h_own = t >> 6;            // head owned in weighted-sum phase
    const int d8    = (t & 63) * 8;      // 8-float slice of D
    const int kk    = t & 15;            // neighbor within chunk (scores phase)
    const int rep   = t >> 4;            // D-slice 32 floats (scores phase)

    for (int ch = 0; ch < 2; ch++) {
        __syncthreads();
        // load chunk of 16 neighbor rows (contiguous 32 KB) into LDS
        {
            const float4* src = (const float4*)(ne + (long)bn * (KK_N * DD) + ch * (16 * DD));
#pragma unroll
            for (int i = 0; i < 8; i++) {
                int f = i * 256 + t;
                float4 v = src[f];
                *(float4*)&ne_s[f >> 7][(f & 127) * 4] = v;
            }
        }
        __syncthreads();
        // scores: 16 k x 4 h dot products of length 512, split 16 ways over D
        {
            float acc[HH] = {};
#pragma unroll
            for (int i = 0; i < 8; i++) {
                float4 nv = *(const float4*)&ne_s[kk][rep * 32 + i * 4];
#pragma unroll
                for (int h = 0; h < HH; h++) {
                    float4 gv = *(const float4*)&g_s[h * DD + rep * 32 + i * 4];
                    acc[h] = fmaf(nv.x, gv.x, acc[h]);
                    acc[h] = fmaf(nv.y, gv.y, acc[h]);
                    acc[h] = fmaf(nv.z, gv.z, acc[h]);
                    acc[h] = fmaf(nv.w, gv.w, acc[h]);
                }
            }
#pragma unroll
            for (int h = 0; h < HH; h++) {
                acc[h] += __shfl_xor(acc[h], 16, 64);
                acc[h] += __shfl_xor(acc[h], 32, 64);
            }
            if ((t & 48) == 0) {
#pragma unroll
                for (int h = 0; h < HH; h++) part[wave][kk][h] = acc[h];
            }
        }
        __syncthreads();
        // online softmax update (wave 0 only; lanes: k_i = bits 0..3, h = bits 4..5)
        if (t < 64) {
            int k_i = t & 15, h = t >> 4;
            float s = part[0][k_i][h] + part[1][k_i][h] + part[2][k_i][h]
                    + part[3][k_i][h] + c_s[h];
            if (mask[(long)bn * KK_N + ch * 16 + k_i] == 0) s = -1.0e9f;
            float mx = s;
#pragma unroll
            for (int off = 8; off >= 1; off >>= 1)
                mx = fmaxf(mx, __shfl_xor(mx, off, 64));
            float m_old = m_s[h];
            float m_new = fmaxf(m_old, mx);
            float p = expf(s - m_new);
            float sm = p;
#pragma unroll
            for (int off = 8; off >= 1; off >>= 1)
                sm += __shfl_xor(sm, off, 64);
            p_s[h][k_i] = p;
            if (k_i == 0) {
                float alpha = expf(m_old - m_new);
                alpha_s[h] = alpha;
                l_s[h] = l_s[h] * alpha + sm;
                m_s[h] = m_new;
            }
        }
        __syncthreads();
        // weighted accumulate: thread owns (h_own, 8 floats of D)
        {
            float alpha = alpha_s[h_own];
#pragma unroll
            for (int j = 0; j < 8; j++) wacc[j] *= alpha;
#pragma unroll
            for (int k2 = 0; k2 < 16; k2++) {
                float pk = p_s[h_own][k2];
                float4 n0 = *(const float4*)&ne_s[k2][d8];
                float4 n1 = *(const float4*)&ne_s[k2][d8 + 4];
                wacc[0] = fmaf(pk, n0.x, wacc[0]);
                wacc[1] = fmaf(pk, n0.y, wacc[1]);
                wacc[2] = fmaf(pk, n0.z, wacc[2]);
                wacc[3] = fmaf(pk, n0.w, wacc[3]);
                wacc[4] = fmaf(pk, n1.x, wacc[4]);
                wacc[5] = fmaf(pk, n1.y, wacc[5]);
                wacc[6] = fmaf(pk, n1.z, wacc[6]);
                wacc[7] = fmaf(pk, n1.w, wacc[7]);
            }
        }
    }
    // finalize: normalize and write wne[bn] (flat offset == t*8 by construction)
    float rl = 1.0f / l_s[h_own];
    float4 o0 = make_float4(wacc[0] * rl, wacc[1] * rl, wacc[2] * rl, wacc[3] * rl);
    float4 o1 = make_float4(wacc[4] * rl, wacc[5] * rl, wacc[6] * rl, wacc[7] * rl);
    float* dst = wne + (long)bn * (HH * DD) + t * 8;
    *(float4*)&dst[0] = o0;
    *(float4*)&dst[4] = o1;
}

// ---------------------------------------------------------------------------
extern "C" void kernel_launch(void* const* d_in, const int* in_sizes, int n_in,
                              void* d_out, int out_size, void* d_ws, size_t ws_size,
                              hipStream_t stream) {
    (void)in_sizes; (void)n_in; (void)out_size; (void)ws_size;
    const float* ne  = (const float*)d_in[0];
    const int*   msk = (const int*)  d_in[1];
    const float* x   = (const float*)d_in[2];
    const float* Wq  = (const float*)d_in[3];
    const float* bq  = (const float*)d_in[4];
    const float* Wk  = (const float*)d_in[5];
    const float* bk  = (const float*)d_in[6];
    const float* Wv  = (const float*)d_in[7];
    const float* bv  = (const float*)d_in[8];
    float* out = (float*)d_out;

    float* q_ws = (float*)d_ws;                       // [4096][512]      8 MB
    float* g_ws = q_ws + (long)BN_TOT * DD;           // [4096][4][512]  32 MB (g, then wne)
    float* wkT  = g_ws + (long)BN_TOT * HH * DD;      // [4][512][128]    1 MB

    dim3 blk(256);
    // 0) WkT[h][o][k] = Wk[h*128+k][o]  (makes step 2 an NT GEMM)
    prep_wkT<<<dim3(16, HH), blk, 0, stream>>>(Wk, wkT);
    // 1) q = x @ Wq^T + bq            M=4096 N=512 K=512; 256 blocks
    gemm_bf16x2<64, 128><<<dim3(DD / 128, BN_TOT / 64, 1), blk, 0, stream>>>(
        x, DD, 0, Wq, DD, 0, q_ws, DD, 0, bq, 0, DD);
    // 2) g[:,h,:] = q_h @ WkT[h]^T    per head: M=4096 N=512 K=128; 1024 blocks
    gemm_bf16x2<64, 128><<<dim3(DD / 128, BN_TOT / 64, HH), blk, 0, stream>>>(
        q_ws, DD, DH, wkT, DH, (long)DD * DH, g_ws, HH * DD, DD, nullptr, 0, DH);
    // 3) fused scores/softmax/weighted-sum -> wne (aliases g_ws)
    attn_fused<<<dim3(BN_TOT), blk, 0, stream>>>(ne, msk, q_ws, g_ws, bk, g_ws);
    // 4) out[:,h*128:] = wne_h @ Wv_h^T + bv_h   per head: M=4096 N=128 K=512; 256 blocks
    gemm_bf16x2<64, 128><<<dim3(1, BN_TOT / 64, HH), blk, 0, stream>>>(
        g_ws, HH * DD, DD, Wv, DD, (long)DH * DD, out, DD, DH, bv, DH, DD);
}